// Round 2
// baseline (169.086 us; speedup 1.0000x reference)
//
#include <hip/hip_runtime.h>
#include <hip/hip_bf16.h>

// Problem constants
#define NB   8      // batch
#define NL   1024   // sequence length
#define ND   256    // model dim
#define NH   8      // heads
#define NHD  64     // head dim
#define NC   512    // NH*NHD
#define NTOK (NB*NL) // 8192

typedef __bf16 bf16x8v __attribute__((ext_vector_type(8)));
typedef float f32x4 __attribute__((ext_vector_type(4)));

__device__ __forceinline__ unsigned short f2bf(float f) {
  unsigned u = __float_as_uint(f);
  unsigned r = (u + 0x7fffu + ((u >> 16) & 1u)) >> 16;
  return (unsigned short)r;
}

// ---------------------------------------------------------------------------
// Prep: xpe = bf16(x + positional_encoding), xb = bf16(x)
// pe[l, 2i] = sin(l / 10000^(2i/256)),  pe[l, 2i+1] = cos(l / 10000^(2i/256))
// ---------------------------------------------------------------------------
__global__ __launch_bounds__(256) void prep_x_kernel(
    const float* __restrict__ x,
    unsigned short* __restrict__ xpe,
    unsigned short* __restrict__ xb) {
  int idx = blockIdx.x * 256 + threadIdx.x;
  if (idx >= NTOK * ND) return;
  int d = idx & (ND - 1);
  int t = idx >> 8;            // ND = 256
  int l = t & (NL - 1);
  float xv = x[idx];
  // 1/dim_t = exp(-ln(10000) * (d>>1) / 128)
  float inv_dim = __expf(-9.210340371976184f * (float)(d >> 1) * (1.0f / 128.0f));
  float ang = (float)l * inv_dim;
  float pe = (d & 1) ? cosf(ang) : sinf(ang);
  xpe[idx] = f2bf(xv + pe);
  xb[idx]  = f2bf(xv);
}

// ---------------------------------------------------------------------------
// Prep: Wt[n][k] = bf16(W[k][n]); W is [256][512] f32 -> Wt [512][256] bf16.
// grid.y in {0,1,2} selects q/k/v weight matrix (one launch for all three).
// ---------------------------------------------------------------------------
__global__ __launch_bounds__(256) void prep_w_kernel(
    const float* __restrict__ Wq, const float* __restrict__ Wk,
    const float* __restrict__ Wv,
    unsigned short* __restrict__ wqt, unsigned short* __restrict__ wkt,
    unsigned short* __restrict__ wvt) {
  int idx = blockIdx.x * 256 + threadIdx.x;
  if (idx >= NC * ND) return;
  const float* W = (blockIdx.y == 0) ? Wq : (blockIdx.y == 1) ? Wk : Wv;
  unsigned short* Wt = (blockIdx.y == 0) ? wqt : (blockIdx.y == 1) ? wkt : wvt;
  int k = idx & (ND - 1);
  int n = idx >> 8;
  Wt[idx] = f2bf(W[k * NC + n]);
}

// ---------------------------------------------------------------------------
// Projection GEMM:  Out = (X[8192x256] * W[256x512] + bias_per_head) * scale
// X, Wt in bf16; MFMA 16x16x32 bf16, tile 128(M) x 64(N), BK=64, 4 waves.
// VLAYOUT 0: Out[(b,h,l,d)]  (q, k)    VLAYOUT 1: Out[(b,h,d,l)]  (v, transposed)
// ---------------------------------------------------------------------------
template <int VLAYOUT>
__global__ __launch_bounds__(256) void gemm_proj_kernel(
    const unsigned short* __restrict__ X,
    const unsigned short* __restrict__ Wt,
    const float* __restrict__ bias, float scale,
    unsigned short* __restrict__ Out) {
  __shared__ unsigned short As[128 * 72];
  __shared__ unsigned short Bs[64 * 72];

  const int nt = blockIdx.x;     // 0..7   N tile
  const int mt = blockIdx.y;     // 0..63  M tile
  const int tid = threadIdx.x;
  const int w = tid >> 6;
  const int lane = tid & 63;
  const int lg = lane >> 4;      // 0..3
  const int lr = lane & 15;      // 0..15

  f32x4 acc[2][4] = {};

  for (int kb = 0; kb < 4; ++kb) {
    // Stage A: 128 rows x 64 cols bf16 (16B per slot, 1024 slots)
#pragma unroll
    for (int i = 0; i < 4; ++i) {
      int slot = tid + i * 256;
      int r = slot >> 3, c8 = slot & 7;
      *(int4*)(As + r * 72 + c8 * 8) =
          *(const int4*)(X + (mt * 128 + r) * ND + kb * 64 + c8 * 8);
    }
    // Stage B (transposed weights): 64 n-rows x 64 k-cols (512 slots)
#pragma unroll
    for (int i = 0; i < 2; ++i) {
      int slot = tid + i * 256;
      int r = slot >> 3, c8 = slot & 7;
      *(int4*)(Bs + r * 72 + c8 * 8) =
          *(const int4*)(Wt + (nt * 64 + r) * ND + kb * 64 + c8 * 8);
    }
    __syncthreads();

#pragma unroll
    for (int kk = 0; kk < 2; ++kk) {
      bf16x8v a[2], b[4];
#pragma unroll
      for (int mi = 0; mi < 2; ++mi)
        a[mi] = *(const bf16x8v*)(As + (w * 32 + mi * 16 + lr) * 72 + kk * 32 + lg * 8);
#pragma unroll
      for (int nb = 0; nb < 4; ++nb)
        b[nb] = *(const bf16x8v*)(Bs + (nb * 16 + lr) * 72 + kk * 32 + lg * 8);
#pragma unroll
      for (int mi = 0; mi < 2; ++mi)
#pragma unroll
        for (int nb = 0; nb < 4; ++nb)
          acc[mi][nb] = __builtin_amdgcn_mfma_f32_16x16x32_bf16(
              a[mi], b[nb], acc[mi][nb], 0, 0, 0);
    }
    __syncthreads();
  }

  // Epilogue: C row = (lane>>4)*4 + j, col = lane&15  [HW-verified layout]
#pragma unroll
  for (int mi = 0; mi < 2; ++mi) {
#pragma unroll
    for (int nb = 0; nb < 4; ++nb) {
#pragma unroll
      for (int j = 0; j < 4; ++j) {
        int r = mt * 128 + w * 32 + mi * 16 + lg * 4 + j;   // token index
        int c = nt * 64 + nb * 16 + lr;                     // column in [0,512)
        int bb = r >> 10, lpos = r & (NL - 1);
        int h = c >> 6, dd = c & 63;
        float val = (acc[mi][nb][j] + bias[h]) * scale;
        if (VLAYOUT == 0)
          Out[((bb * NH + h) * NL + lpos) * NHD + dd] = f2bf(val);
        else
          Out[((bb * NH + h) * NHD + dd) * NL + lpos] = f2bf(val);
      }
    }
  }
}

// ---------------------------------------------------------------------------
// Flash attention: grid (16 q-tiles, 64 bh), 256 threads = 4 waves.
// Each wave owns 16 q-rows. KV tiles of 64. Q/K layout [B,H,L,hd] bf16;
// V pre-transposed [B,H,hd,L] bf16. Scale already folded into Q.
// ---------------------------------------------------------------------------
__global__ __launch_bounds__(256) void attn_kernel(
    const unsigned short* __restrict__ Q,
    const unsigned short* __restrict__ K,
    const unsigned short* __restrict__ Vt,
    float* __restrict__ Out) {
  __shared__ unsigned short Ks[64 * 72];
  __shared__ unsigned short Vs[64 * 72];
  __shared__ unsigned short Ps[64 * 72];

  const int qt = blockIdx.x;   // 0..15
  const int bh = blockIdx.y;   // 0..63
  const int bb = bh >> 3, h = bh & 7;
  const int tid = threadIdx.x;
  const int w = tid >> 6;
  const int lane = tid & 63;
  const int lg = lane >> 4, lr = lane & 15;
  const int qrow0 = qt * 64 + w * 16;

  // Q fragments (row = lr, k-slice = lg*8 within each 32-block)
  bf16x8v qf[2];
#pragma unroll
  for (int kk = 0; kk < 2; ++kk)
    qf[kk] = *(const bf16x8v*)(Q + ((size_t)bh * NL + qrow0 + lr) * NHD + kk * 32 + lg * 8);

  float m_[4], lsum[4];
  f32x4 o[4] = {};
#pragma unroll
  for (int j = 0; j < 4; ++j) { m_[j] = -1e30f; lsum[j] = 0.0f; }

  for (int kv = 0; kv < 16; ++kv) {
    // Stage K tile [64 rows][64 dims] and Vt tile [64 dims][64 kv-cols]
#pragma unroll
    for (int i = 0; i < 2; ++i) {
      int slot = tid + i * 256;
      int r = slot >> 3, c8 = slot & 7;
      *(int4*)(Ks + r * 72 + c8 * 8) =
          *(const int4*)(K + ((size_t)bh * NL + kv * 64 + r) * NHD + c8 * 8);
      *(int4*)(Vs + r * 72 + c8 * 8) =
          *(const int4*)(Vt + ((size_t)bh * NHD + r) * NL + kv * 64 + c8 * 8);
    }
    __syncthreads();

    // S = Q * K^T  (16 x 64 per wave)
    f32x4 s[4] = {};
#pragma unroll
    for (int kk = 0; kk < 2; ++kk) {
#pragma unroll
      for (int nb = 0; nb < 4; ++nb) {
        bf16x8v kf = *(const bf16x8v*)(Ks + (nb * 16 + lr) * 72 + kk * 32 + lg * 8);
        s[nb] = __builtin_amdgcn_mfma_f32_16x16x32_bf16(qf[kk], kf, s[nb], 0, 0, 0);
      }
    }

    // Online softmax per row (rows lg*4+j; cols lr + 16*nb)
    float corr[4];
#pragma unroll
    for (int j = 0; j < 4; ++j) {
      float tm = fmaxf(fmaxf(s[0][j], s[1][j]), fmaxf(s[2][j], s[3][j]));
      tm = fmaxf(tm, __shfl_xor(tm, 1, 64));
      tm = fmaxf(tm, __shfl_xor(tm, 2, 64));
      tm = fmaxf(tm, __shfl_xor(tm, 4, 64));
      tm = fmaxf(tm, __shfl_xor(tm, 8, 64));
      float nm = fmaxf(m_[j], tm);
      corr[j] = __expf(m_[j] - nm);
      m_[j] = nm;
      float ts = 0.0f;
#pragma unroll
      for (int nb = 0; nb < 4; ++nb) {
        float p = __expf(s[nb][j] - nm);
        s[nb][j] = p;
        ts += p;
      }
      ts += __shfl_xor(ts, 1, 64);
      ts += __shfl_xor(ts, 2, 64);
      ts += __shfl_xor(ts, 4, 64);
      ts += __shfl_xor(ts, 8, 64);
      lsum[j] = lsum[j] * corr[j] + ts;
#pragma unroll
      for (int db = 0; db < 4; ++db) o[db][j] *= corr[j];
    }

    // P -> bf16 via wave-private LDS bounce (re-fragment rows to lane&15)
#pragma unroll
    for (int nb = 0; nb < 4; ++nb)
#pragma unroll
      for (int j = 0; j < 4; ++j)
        Ps[(w * 16 + lg * 4 + j) * 72 + nb * 16 + lr] = f2bf(s[nb][j]);

    // O += P * V
#pragma unroll
    for (int kk = 0; kk < 2; ++kk) {
      bf16x8v pf = *(const bf16x8v*)(Ps + (w * 16 + lr) * 72 + kk * 32 + lg * 8);
#pragma unroll
      for (int db = 0; db < 4; ++db) {
        bf16x8v vf = *(const bf16x8v*)(Vs + (db * 16 + lr) * 72 + kk * 32 + lg * 8);
        o[db] = __builtin_amdgcn_mfma_f32_16x16x32_bf16(pf, vf, o[db], 0, 0, 0);
      }
    }
    __syncthreads();
  }

  // Normalize and write out[B, L, 512] f32
#pragma unroll
  for (int j = 0; j < 4; ++j) {
    float inv = 1.0f / lsum[j];
    int r = qt * 64 + w * 16 + lg * 4 + j;
#pragma unroll
    for (int db = 0; db < 4; ++db)
      Out[((size_t)(bb * NL + r)) * NC + h * NHD + db * 16 + lr] = o[db][j] * inv;
  }
}

// ---------------------------------------------------------------------------
extern "C" void kernel_launch(void* const* d_in, const int* in_sizes, int n_in,
                              void* d_out, int out_size, void* d_ws, size_t ws_size,
                              hipStream_t stream) {
  const float* x  = (const float*)d_in[0];
  const float* Wq = (const float*)d_in[1];
  const float* bq = (const float*)d_in[2];
  const float* Wk = (const float*)d_in[3];
  const float* bk = (const float*)d_in[4];
  const float* Wv = (const float*)d_in[5];
  const float* bv = (const float*)d_in[6];
  float* out = (float*)d_out;

  // Workspace layout (all bf16 stored as ushort)
  unsigned short* xpe = (unsigned short*)d_ws;        // 2M elems
  unsigned short* xb  = xpe + (size_t)NTOK * ND;      // 2M
  unsigned short* wqt = xb  + (size_t)NTOK * ND;      // 128K
  unsigned short* wkt = wqt + (size_t)ND * NC;
  unsigned short* wvt = wkt + (size_t)ND * NC;
  unsigned short* qg  = wvt + (size_t)ND * NC;        // 512K each
  unsigned short* kg  = qg  + (size_t)NB * NH * NL * NHD;
  unsigned short* vg  = kg  + (size_t)NB * NH * NL * NHD;

  prep_x_kernel<<<(NTOK * ND) / 256, 256, 0, stream>>>(x, xpe, xb);
  prep_w_kernel<<<dim3((NC * ND) / 256, 3), 256, 0, stream>>>(
      Wq, Wk, Wv, wqt, wkt, wvt);

  dim3 ggrid(8, 64);
  // q: fold attention scale 1/sqrt(64) = 0.125 into q
  gemm_proj_kernel<0><<<ggrid, 256, 0, stream>>>(xpe, wqt, bq, 0.125f, qg);
  gemm_proj_kernel<0><<<ggrid, 256, 0, stream>>>(xpe, wkt, bk, 1.0f, kg);
  gemm_proj_kernel<1><<<ggrid, 256, 0, stream>>>(xb,  wvt, bv, 1.0f, vg);

  attn_kernel<<<dim3(16, 64), 256, 0, stream>>>(qg, kg, vg, out);
}

// Round 3
// 154.981 us; speedup vs baseline: 1.0910x; 1.0910x over previous
//
#include <hip/hip_runtime.h>
#include <hip/hip_bf16.h>

// Problem constants
#define NB   8      // batch
#define NL   1024   // sequence length
#define ND   256    // model dim
#define NH   8      // heads
#define NHD  64     // head dim
#define NC   512    // NH*NHD
#define NTOK (NB*NL) // 8192

typedef __bf16 bf16x8v __attribute__((ext_vector_type(8)));
typedef float f32x4 __attribute__((ext_vector_type(4)));

__device__ __forceinline__ unsigned short f2bf(float f) {
  unsigned u = __float_as_uint(f);
  unsigned r = (u + 0x7fffu + ((u >> 16) & 1u)) >> 16;
  return (unsigned short)r;
}

// pack two f32 -> bf16x2 (elem0 in low 16 bits); compiler emits v_cvt_pk path
__device__ __forceinline__ unsigned pack_bf16x2(float lo, float hi) {
  __hip_bfloat162 h2 = __float22bfloat162_rn(make_float2(lo, hi));
  union { __hip_bfloat162 h; unsigned u; } cvt;
  cvt.h = h2;
  return cvt.u;
}

// ---------------------------------------------------------------------------
// Fused prep: blocks [0, 8192): xpe = bf16(x + PE), xb = bf16(x)
//             blocks [8192, 9728): Wt[n][k] = bf16(W[k][n]) for q,k,v weights
// ---------------------------------------------------------------------------
__global__ __launch_bounds__(256) void prep_kernel(
    const float* __restrict__ x,
    const float* __restrict__ Wq, const float* __restrict__ Wk,
    const float* __restrict__ Wv,
    unsigned short* __restrict__ xpe, unsigned short* __restrict__ xb,
    unsigned short* __restrict__ wqt, unsigned short* __restrict__ wkt,
    unsigned short* __restrict__ wvt) {
  int bid = blockIdx.x;
  if (bid < (NTOK * ND) / 256) {
    int idx = bid * 256 + threadIdx.x;
    int d = idx & (ND - 1);
    int t = idx >> 8;            // ND = 256
    int l = t & (NL - 1);
    float xv = x[idx];
    float inv_dim = __expf(-9.210340371976184f * (float)(d >> 1) * (1.0f / 128.0f));
    float ang = (float)l * inv_dim;
    float pe = (d & 1) ? cosf(ang) : sinf(ang);
    xpe[idx] = f2bf(xv + pe);
    xb[idx]  = f2bf(xv);
  } else {
    int idx = (bid - (NTOK * ND) / 256) * 256 + threadIdx.x;   // 0 .. 3*131072
    int m = idx >> 17;                                          // which matrix
    int r = idx & (NC * ND - 1);                                // 131072 = 2^17
    const float* W = (m == 0) ? Wq : (m == 1) ? Wk : Wv;
    unsigned short* Wt = (m == 0) ? wqt : (m == 1) ? wkt : wvt;
    int k = r & (ND - 1);
    int n = r >> 8;
    Wt[r] = f2bf(W[k * NC + n]);
  }
}

// ---------------------------------------------------------------------------
// Fused QKV projection GEMM: grid.z in {0:q, 1:k, 2:v}
// Out = (X[8192x256] * W[256x512] + bias_per_head) * scale
// MFMA 16x16x32 bf16, tile 128(M) x 64(N), BK=64, 4 waves.
// z<2: Out[(b,h,l,d)]   z==2 (v): Out[(b,h,d,l)] (transposed for attention)
// ---------------------------------------------------------------------------
__global__ __launch_bounds__(256) void gemm_qkv_kernel(
    const unsigned short* __restrict__ xpe, const unsigned short* __restrict__ xb,
    const unsigned short* __restrict__ wqt, const unsigned short* __restrict__ wkt,
    const unsigned short* __restrict__ wvt,
    const float* __restrict__ bq, const float* __restrict__ bk,
    const float* __restrict__ bv,
    unsigned short* __restrict__ qg, unsigned short* __restrict__ kg,
    unsigned short* __restrict__ vg) {
  __shared__ unsigned short As[128 * 72];
  __shared__ unsigned short Bs[64 * 72];

  const int z = blockIdx.z;
  const unsigned short* X  = (z == 2) ? xb : xpe;
  const unsigned short* Wt = (z == 0) ? wqt : (z == 1) ? wkt : wvt;
  const float* bias        = (z == 0) ? bq  : (z == 1) ? bk  : bv;
  unsigned short* Out      = (z == 0) ? qg  : (z == 1) ? kg  : vg;
  const float scale        = (z == 0) ? 0.125f : 1.0f;   // fold 1/sqrt(64) into q

  const int nt = blockIdx.x;     // 0..7   N tile
  const int mt = blockIdx.y;     // 0..63  M tile
  const int tid = threadIdx.x;
  const int w = tid >> 6;
  const int lane = tid & 63;
  const int lg = lane >> 4;      // 0..3
  const int lr = lane & 15;      // 0..15

  f32x4 acc[2][4] = {};

  for (int kb = 0; kb < 4; ++kb) {
#pragma unroll
    for (int i = 0; i < 4; ++i) {
      int slot = tid + i * 256;
      int r = slot >> 3, c8 = slot & 7;
      *(int4*)(As + r * 72 + c8 * 8) =
          *(const int4*)(X + (mt * 128 + r) * ND + kb * 64 + c8 * 8);
    }
#pragma unroll
    for (int i = 0; i < 2; ++i) {
      int slot = tid + i * 256;
      int r = slot >> 3, c8 = slot & 7;
      *(int4*)(Bs + r * 72 + c8 * 8) =
          *(const int4*)(Wt + (nt * 64 + r) * ND + kb * 64 + c8 * 8);
    }
    __syncthreads();

#pragma unroll
    for (int kk = 0; kk < 2; ++kk) {
      bf16x8v a[2], b[4];
#pragma unroll
      for (int mi = 0; mi < 2; ++mi)
        a[mi] = *(const bf16x8v*)(As + (w * 32 + mi * 16 + lr) * 72 + kk * 32 + lg * 8);
#pragma unroll
      for (int nb = 0; nb < 4; ++nb)
        b[nb] = *(const bf16x8v*)(Bs + (nb * 16 + lr) * 72 + kk * 32 + lg * 8);
#pragma unroll
      for (int mi = 0; mi < 2; ++mi)
#pragma unroll
        for (int nb = 0; nb < 4; ++nb)
          acc[mi][nb] = __builtin_amdgcn_mfma_f32_16x16x32_bf16(
              a[mi], b[nb], acc[mi][nb], 0, 0, 0);
    }
    __syncthreads();
  }

  // C row = (lane>>4)*4 + j, col = lane&15  [HW-verified layout]
#pragma unroll
  for (int mi = 0; mi < 2; ++mi) {
#pragma unroll
    for (int nb = 0; nb < 4; ++nb) {
#pragma unroll
      for (int j = 0; j < 4; ++j) {
        int r = mt * 128 + w * 32 + mi * 16 + lg * 4 + j;   // token index
        int c = nt * 64 + nb * 16 + lr;                     // column in [0,512)
        int bb = r >> 10, lpos = r & (NL - 1);
        int h = c >> 6, dd = c & 63;
        float val = (acc[mi][nb][j] + bias[h]) * scale;
        if (z < 2)
          Out[((bb * NH + h) * NL + lpos) * NHD + dd] = f2bf(val);
        else
          Out[((bb * NH + h) * NHD + dd) * NL + lpos] = f2bf(val);
      }
    }
  }
}

// ---------------------------------------------------------------------------
// Flash attention, swapped-operand form: grid (16 q-tiles, 64 bh), 4 waves.
// Each wave owns 16 q-rows; per lane the whole q-row (q = lane&15) is local:
//   S^T = mfma(kf, qf)  ->  lane(lr,lg) holds S[q=lr][k=16nb+4lg+j]
//   O^T = mfma(vf, pf)  ->  lane(lr,lg) holds O[d=16db+4lg+j][q=lr]
// so softmax max/sum need only xor-16/32 shuffles and corr/lsum are scalars.
// Q/K layout [B,H,L,hd] bf16; V pre-transposed [B,H,hd,L] bf16.
// ---------------------------------------------------------------------------
__global__ __launch_bounds__(256) void attn_kernel(
    const unsigned short* __restrict__ Q,
    const unsigned short* __restrict__ K,
    const unsigned short* __restrict__ Vt,
    float* __restrict__ Out) {
  __shared__ unsigned short Ks[64 * 72];
  __shared__ unsigned short Vs[64 * 72];
  __shared__ unsigned short Ps[64 * 72];

  const int qt = blockIdx.x;   // 0..15
  const int bh = blockIdx.y;   // 0..63
  const int bb = bh >> 3, h = bh & 7;
  const int tid = threadIdx.x;
  const int w = tid >> 6;
  const int lane = tid & 63;
  const int lg = lane >> 4, lr = lane & 15;
  const int qrow0 = qt * 64 + w * 16;

  // Q B-fragment: row = lr, k-slice = lg*8 within each 32-block (unchanged)
  bf16x8v qf[2];
#pragma unroll
  for (int kk = 0; kk < 2; ++kk)
    qf[kk] = *(const bf16x8v*)(Q + ((size_t)bh * NL + qrow0 + lr) * NHD + kk * 32 + lg * 8);

  float m_ = -1e30f, lsum = 0.0f;
  f32x4 o[4] = {};

  for (int kv = 0; kv < 16; ++kv) {
    // Stage K tile [64 kv-rows][64 dims] and Vt tile [64 dims][64 kv-cols]
#pragma unroll
    for (int i = 0; i < 2; ++i) {
      int slot = tid + i * 256;
      int r = slot >> 3, c8 = slot & 7;
      *(int4*)(Ks + r * 72 + c8 * 8) =
          *(const int4*)(K + ((size_t)bh * NL + kv * 64 + r) * NHD + c8 * 8);
      *(int4*)(Vs + r * 72 + c8 * 8) =
          *(const int4*)(Vt + ((size_t)bh * NHD + r) * NL + kv * 64 + c8 * 8);
    }
    __syncthreads();

    // S^T = K * Q^T: lane(lr,lg) gets S[q=lr][k=nb*16+lg*4+j]
    f32x4 s[4] = {};
#pragma unroll
    for (int kk = 0; kk < 2; ++kk) {
#pragma unroll
      for (int nb = 0; nb < 4; ++nb) {
        bf16x8v kf = *(const bf16x8v*)(Ks + (nb * 16 + lr) * 72 + kk * 32 + lg * 8);
        s[nb] = __builtin_amdgcn_mfma_f32_16x16x32_bf16(kf, qf[kk], s[nb], 0, 0, 0);
      }
    }

    // Online softmax: 16 in-lane values + xor-16/32 across the 4 lg groups
    float tm = s[0][0];
#pragma unroll
    for (int nb = 0; nb < 4; ++nb)
#pragma unroll
      for (int j = 0; j < 4; ++j) tm = fmaxf(tm, s[nb][j]);
    tm = fmaxf(tm, __shfl_xor(tm, 16, 64));
    tm = fmaxf(tm, __shfl_xor(tm, 32, 64));
    float nm = fmaxf(m_, tm);
    float corr = __expf(m_ - nm);
    m_ = nm;
    float ts = 0.0f;
#pragma unroll
    for (int nb = 0; nb < 4; ++nb)
#pragma unroll
      for (int j = 0; j < 4; ++j) {
        float p = __expf(s[nb][j] - nm);
        s[nb][j] = p;
        ts += p;
      }
    ts += __shfl_xor(ts, 16, 64);
    ts += __shfl_xor(ts, 32, 64);
    lsum = lsum * corr + ts;
#pragma unroll
    for (int db = 0; db < 4; ++db)
#pragma unroll
      for (int j = 0; j < 4; ++j) o[db][j] *= corr;

    // P row q=lr -> LDS, packed u32 at k/2 (k = 16nb+4lg+2h): conflict-free
#pragma unroll
    for (int nb = 0; nb < 4; ++nb)
#pragma unroll
      for (int hh = 0; hh < 2; ++hh)
        *(unsigned*)(Ps + (w * 16 + lr) * 72 + nb * 16 + lg * 4 + 2 * hh) =
            pack_bf16x2(s[nb][2 * hh], s[nb][2 * hh + 1]);

    // O^T += V^T * P^T : pf read address identical to the verified GEMM path
#pragma unroll
    for (int kk = 0; kk < 2; ++kk) {
      bf16x8v pf = *(const bf16x8v*)(Ps + (w * 16 + lr) * 72 + kk * 32 + lg * 8);
#pragma unroll
      for (int db = 0; db < 4; ++db) {
        bf16x8v vf = *(const bf16x8v*)(Vs + (db * 16 + lr) * 72 + kk * 32 + lg * 8);
        o[db] = __builtin_amdgcn_mfma_f32_16x16x32_bf16(vf, pf, o[db], 0, 0, 0);
      }
    }
    __syncthreads();
  }

  // Normalize (scalar per lane) and write out[B, L, 512] f32 as float4s
  float inv = 1.0f / lsum;
  int q = qrow0 + lr;
#pragma unroll
  for (int db = 0; db < 4; ++db) {
    f32x4 ov;
#pragma unroll
    for (int j = 0; j < 4; ++j) ov[j] = o[db][j] * inv;
    *(f32x4*)(Out + (size_t)(bb * NL + q) * NC + h * NHD + db * 16 + lg * 4) = ov;
  }
}

// ---------------------------------------------------------------------------
extern "C" void kernel_launch(void* const* d_in, const int* in_sizes, int n_in,
                              void* d_out, int out_size, void* d_ws, size_t ws_size,
                              hipStream_t stream) {
  const float* x  = (const float*)d_in[0];
  const float* Wq = (const float*)d_in[1];
  const float* bq = (const float*)d_in[2];
  const float* Wk = (const float*)d_in[3];
  const float* bk = (const float*)d_in[4];
  const float* Wv = (const float*)d_in[5];
  const float* bv = (const float*)d_in[6];
  float* out = (float*)d_out;

  // Workspace layout (all bf16 stored as ushort)
  unsigned short* xpe = (unsigned short*)d_ws;        // 2M elems
  unsigned short* xb  = xpe + (size_t)NTOK * ND;      // 2M
  unsigned short* wqt = xb  + (size_t)NTOK * ND;      // 128K
  unsigned short* wkt = wqt + (size_t)ND * NC;
  unsigned short* wvt = wkt + (size_t)ND * NC;
  unsigned short* qg  = wvt + (size_t)ND * NC;        // 512K each
  unsigned short* kg  = qg  + (size_t)NB * NH * NL * NHD;
  unsigned short* vg  = kg  + (size_t)NB * NH * NL * NHD;

  int prep_blocks = (NTOK * ND) / 256 + 3 * (NC * ND) / 256;   // 8192 + 1536
  prep_kernel<<<prep_blocks, 256, 0, stream>>>(x, Wq, Wk, Wv, xpe, xb, wqt, wkt, wvt);

  gemm_qkv_kernel<<<dim3(8, 64, 3), 256, 0, stream>>>(
      xpe, xb, wqt, wkt, wvt, bq, bk, bv, qg, kg, vg);

  attn_kernel<<<dim3(16, 64), 256, 0, stream>>>(qg, kg, vg, out);
}